// Round 14
// baseline (524.421 us; speedup 1.0000x reference)
//
#include <hip/hip_runtime.h>
#include <hip/hip_cooperative_groups.h>

namespace cg = cooperative_groups;

#define N_NODES  100000
#define N_EDGES  3200000
#define N_GRAPHS 512
#define F_IN     5
#define F_HID    16

#define NTHR   256
#define CHUNK  2048                     // edges per partition chunk
#define EPT    (CHUNK / NTHR)           // 8
#define NCHUNK ((N_EDGES + CHUNK - 1) / CHUNK)          // 1563
#define CNT_NODES 64                    // nodes per chunk for graph counting
#define BKT_NODES 128                   // nodes per bucket
#define BKT_SHIFT 7
#define NBKT ((N_NODES + BKT_NODES - 1) / BKT_NODES)    // 782
#define SHARDS 8                        // cursor shards per bucket
#define CAP_S  768                      // per-(bucket,shard): mean 512, +11 sigma
#define CAP    (SHARDS * CAP_S)         // 6144 per bucket
#define NWIN   (N_NODES / 32)           // 3125 pull windows (32 nodes each)

// ---------------- helpers ----------------

__device__ inline unsigned short f2bf(float f) {
    unsigned u = __float_as_uint(f);
    return (unsigned short)((u + 0x7fffu + ((u >> 16) & 1u)) >> 16);   // RNE
}
__device__ inline float bf2f(unsigned short h) {
    return __uint_as_float(((unsigned)h) << 16);
}
__device__ inline float4 cvt4(ushort4 u) {
    return make_float4(bf2f(u.x), bf2f(u.y), bf2f(u.z), bf2f(u.w));
}
__device__ inline float4 shfl_xor4(float4 v, int m) {
    return make_float4(__shfl_xor(v.x, m, 64), __shfl_xor(v.y, m, 64),
                       __shfl_xor(v.z, m, 64), __shfl_xor(v.w, m, 64));
}

// 128-wide inclusive scan with 256 threads (values live in t<128)
__device__ inline int scan128(int v, int t, int* wsum) {
    int lane = t & 63, wave = t >> 6;
    int x = v;
#pragma unroll
    for (int o = 1; o < 64; o <<= 1) {
        int y = __shfl_up(x, o, 64);
        if (lane >= o) x += y;
    }
    if (lane == 63) wsum[wave] = x;
    __syncthreads();
    if (t < 64) {
        int w = (t < 4) ? wsum[t] : 0;
#pragma unroll
        for (int o = 1; o < 4; o <<= 1) {
            int y = __shfl_up(w, o, 64);
            if (t >= o) w += y;
        }
        if (t < 4) wsum[t] = w;
    }
    __syncthreads();
    return x + (wave ? wsum[wave - 1] : 0);
}

// half-row gather (len % 8 == 0): half h takes 8-blocks h, h+2, ... (R9-proven)
__device__ inline float4 row_gather8s(const ushort4* __restrict__ pb4, int i, int j,
                                      int half, int beg, int len,
                                      const int* __restrict__ col) {
    float4 acc = half ? make_float4(0.f, 0.f, 0.f, 0.f)
                      : cvt4(pb4[i * 4 + j]);          // self loop once
    for (int k = half * 8; k < len; k += 16) {
        int4 c0 = *(const int4*)(col + beg + k);
        int4 c1 = *(const int4*)(col + beg + k + 4);
        ushort4 a0 = pb4[c0.x * 4 + j], a1 = pb4[c0.y * 4 + j];
        ushort4 a2 = pb4[c0.z * 4 + j], a3 = pb4[c0.w * 4 + j];
        ushort4 a4 = pb4[c1.x * 4 + j], a5 = pb4[c1.y * 4 + j];
        ushort4 a6 = pb4[c1.z * 4 + j], a7 = pb4[c1.w * 4 + j];
        float4 f0 = cvt4(a0), f1 = cvt4(a1), f2 = cvt4(a2), f3 = cvt4(a3);
        float4 f4 = cvt4(a4), f5 = cvt4(a5), f6 = cvt4(a6), f7 = cvt4(a7);
        acc.x += ((f0.x + f1.x) + (f2.x + f3.x)) + ((f4.x + f5.x) + (f6.x + f7.x));
        acc.y += ((f0.y + f1.y) + (f2.y + f3.y)) + ((f4.y + f5.y) + (f6.y + f7.y));
        acc.z += ((f0.z + f1.z) + (f2.z + f3.z)) + ((f4.z + f5.z) + (f6.z + f7.z));
        acc.w += ((f0.w + f1.w) + (f2.w + f3.w)) + ((f4.w + f5.w) + (f6.w + f7.w));
    }
    return acc;
}

// ---------------- phase device functions (shared by fused + split) ----------------

__device__ inline void phase_part(int c, const int* __restrict__ src,
                                  const int* __restrict__ dst,
                                  const int* __restrict__ batch,
                                  int* __restrict__ cursor,
                                  unsigned* __restrict__ packed,
                                  float* __restrict__ cnt) {
    __shared__ int hist[NBKT];
    __shared__ int gbase[NBKT];
    __shared__ int bcnt[8];
    __shared__ int g0s;
    int t = threadIdx.x;
    int s = c & (SHARDS - 1);
    int chunk0 = c * CHUNK;
    int n = min(CHUNK, N_EDGES - chunk0);
    for (int i = t; i < NBKT; i += NTHR) hist[i] = 0;
    if (t < 8) bcnt[t] = 0;
    if (t == 0) {
        int nb = c * CNT_NODES;
        g0s = batch[nb < N_NODES ? nb : N_NODES - 1];
    }
    __syncthreads();
    int ls[EPT], ld[EPT], lr[EPT];
#pragma unroll
    for (int idx = 0; idx < EPT; idx++) {
        int k = t + idx * NTHR;
        if (k < n) {
            ls[idx] = src[chunk0 + k];
            ld[idx] = dst[chunk0 + k];
            lr[idx] = atomicAdd(&hist[ld[idx] >> BKT_SHIFT], 1);   // rank capture
        }
    }
    if (t < CNT_NODES) {                 // graph-size count for node window
        int i2 = c * CNT_NODES + t;
        if (i2 < N_NODES) {
            int g = batch[i2];
            int l = g - g0s;
            if (l >= 0 && l < 8) atomicAdd(&bcnt[l], 1);
            else atomicAdd(&cnt[g], 1.0f);
        }
    }
    __syncthreads();
    for (int b = t; b < NBKT; b += NTHR) {
        int v = hist[b];
        gbase[b] = (v > 0) ? atomicAdd(&cursor[b * SHARDS + s], v) : 0;
    }
    if (t < 8 && bcnt[t] > 0) atomicAdd(&cnt[g0s + t], (float)bcnt[t]);
    __syncthreads();
#pragma unroll
    for (int idx = 0; idx < EPT; idx++) {
        int k = t + idx * NTHR;
        if (k < n) {
            int b = ld[idx] >> BKT_SHIFT;
            int g = gbase[b] + lr[idx];
            if (g < CAP_S)
                packed[(size_t)b * CAP + s * CAP_S + g] =
                    ((unsigned)ls[idx] << BKT_SHIFT) |
                    (unsigned)(ld[idx] & (BKT_NODES - 1));
        }
    }
    __syncthreads();                     // hist/gbase reused next iteration
}

__device__ inline void phase_csr(int b, const int* __restrict__ cursor,
                                 const unsigned* __restrict__ packed,
                                 const float* __restrict__ x,
                                 const float* __restrict__ W1,
                                 int2* __restrict__ rowbc, int* __restrict__ col,
                                 float* __restrict__ dinv,
                                 unsigned short* __restrict__ pb) {
    __shared__ int chist[BKT_NODES];
    __shared__ int crnk[BKT_NODES];
    __shared__ int wsum[4];
    __shared__ int ns[SHARDS];
    __shared__ float w1[F_IN * F_HID];
    int t = threadIdx.x;
    int base = b * CAP;
    if (t < BKT_NODES) chist[t] = 0;
    if (t < SHARDS) ns[t] = min(cursor[b * SHARDS + t], CAP_S);
    if (t < F_IN * F_HID) w1[t] = W1[t];
    __syncthreads();
    const unsigned* pk = packed + (size_t)b * CAP;
#pragma unroll
    for (int s = 0; s < SHARDS; s++) {
        int m = ns[s];
        const unsigned* pks = pk + s * CAP_S;
        for (int k = t; k < m; k += NTHR)
            atomicAdd(&chist[pks[k] & (BKT_NODES - 1)], 1);
    }
    __syncthreads();
    int v = (t < BKT_NODES) ? chist[t] : 0;
    int len = (v + 7) & ~7;
    int incl = scan128(len, t, wsum);
    int excl = incl - len;
    if (t < BKT_NODES) crnk[t] = excl;
    __syncthreads();
#pragma unroll
    for (int s = 0; s < SHARDS; s++) {
        int m = ns[s];
        const unsigned* pks = pk + s * CAP_S;
        for (int k = t; k < m; k += NTHR) {
            unsigned w = pks[k];
            int r = atomicAdd(&crnk[w & (BKT_NODES - 1)], 1);
            if (r < CAP) col[base + r] = (int)(w >> BKT_SHIFT);
        }
    }
    if (t < BKT_NODES) {
        int node = b * BKT_NODES + t;
        if (node < N_NODES) {
            int mylen = min(len, ((CAP - min(excl, CAP)) & ~7));
            for (int q = v; q < mylen; q++) {          // pad with dummy node
                int r = excl + q;
                if (r < CAP) col[base + r] = N_NODES;
            }
            rowbc[node] = make_int2(base + excl, mylen);
            float di = rsqrtf((float)(1 + v));
            dinv[node] = di;
            float xi[F_IN];
#pragma unroll
            for (int k = 0; k < F_IN; k++) xi[k] = x[node * F_IN + k];
            float hv[F_HID];
#pragma unroll
            for (int c = 0; c < F_HID; c++) {
                float h = 0.0f;
#pragma unroll
                for (int k = 0; k < F_IN; k++) h += xi[k] * w1[k * F_HID + c];
                hv[c] = h * di;
            }
            unsigned pkk[8];
#pragma unroll
            for (int q = 0; q < 8; q++)
                pkk[q] = (unsigned)f2bf(hv[2 * q]) |
                         ((unsigned)f2bf(hv[2 * q + 1]) << 16);
            uint4* d4 = (uint4*)(pb + (size_t)node * F_HID);
            d4[0] = make_uint4(pkk[0], pkk[1], pkk[2], pkk[3]);
            d4[1] = make_uint4(pkk[4], pkk[5], pkk[6], pkk[7]);
        }
    }
    __syncthreads();                     // chist/crnk reused next iteration
}

__device__ inline void phase_mid(int w, const int2* __restrict__ rowbc,
                                 const int* __restrict__ col,
                                 const unsigned short* __restrict__ pb,
                                 const float* __restrict__ dinv,
                                 const float* __restrict__ W2,
                                 const float* __restrict__ b1,
                                 unsigned short* __restrict__ pb2) {
    __shared__ float w2s[F_HID * F_HID];
    __shared__ float bb1[F_HID];
    int t = threadIdx.x;
    w2s[t] = W2[t];
    if (t < F_HID) bb1[t] = b1[t];
    __syncthreads();
    int half = (t >> 2) & 1, j = t & 3, nl = t >> 3;
    int i = w * 32 + nl;
    int2 rc = rowbc[i];
    float4 acc = row_gather8s((const ushort4*)pb, i, j, half, rc.x, rc.y, col);
    acc.x += __shfl_xor(acc.x, 4, 64);
    acc.y += __shfl_xor(acc.y, 4, 64);
    acc.z += __shfl_xor(acc.z, 4, 64);
    acc.w += __shfl_xor(acc.w, 4, 64);
    float di = dinv[i];
    float4 mine;
    mine.x = fmaxf(di * acc.x + bb1[4 * j + 0], 0.0f);
    mine.y = fmaxf(di * acc.y + bb1[4 * j + 1], 0.0f);
    mine.z = fmaxf(di * acc.z + bb1[4 * j + 2], 0.0f);
    mine.w = fmaxf(di * acc.w + bb1[4 * j + 3], 0.0f);
    float4 o1 = shfl_xor4(mine, 1);
    float4 o2 = shfl_xor4(mine, 2);
    float4 o3 = shfl_xor4(mine, 3);
    float4 hq0 = (j == 0) ? mine : ((j == 1) ? o1 : ((j == 2) ? o2 : o3));
    float4 hq1 = (j == 1) ? mine : ((j == 0) ? o1 : ((j == 3) ? o2 : o3));
    float4 hq2 = (j == 2) ? mine : ((j == 3) ? o1 : ((j == 0) ? o2 : o3));
    float4 hq3 = (j == 3) ? mine : ((j == 2) ? o1 : ((j == 1) ? o2 : o3));
    float hc[F_HID] = {hq0.x, hq0.y, hq0.z, hq0.w, hq1.x, hq1.y, hq1.z, hq1.w,
                       hq2.x, hq2.y, hq2.z, hq2.w, hq3.x, hq3.y, hq3.z, hq3.w};
    float m0 = 0.0f, m1 = 0.0f, m2 = 0.0f, m3 = 0.0f;
#pragma unroll
    for (int c = 0; c < F_HID; c++) {
        float4 wv = *(const float4*)&w2s[c * F_HID + 4 * j];
        float hv = hc[c];
        m0 += hv * wv.x; m1 += hv * wv.y; m2 += hv * wv.z; m3 += hv * wv.w;
    }
    if (half == 0) {
        unsigned p0 = (unsigned)f2bf(m0 * di) | ((unsigned)f2bf(m1 * di) << 16);
        unsigned p1 = (unsigned)f2bf(m2 * di) | ((unsigned)f2bf(m3 * di) << 16);
        *(uint2*)(pb2 + (size_t)i * F_HID + 4 * j) = make_uint2(p0, p1);
    }
    __syncthreads();
}

__device__ inline void phase_pool(int w, const int2* __restrict__ rowbc,
                                  const int* __restrict__ col,
                                  const unsigned short* __restrict__ pb,
                                  const float* __restrict__ dinv,
                                  const int* __restrict__ batch,
                                  const float* __restrict__ b2,
                                  const float* __restrict__ cnt,
                                  float* __restrict__ out) {
    __shared__ float bb2[F_HID];
    __shared__ float acc2[8][F_HID];
    __shared__ int gcnt[8];
    __shared__ int pg0;
    int t = threadIdx.x;
    if (t < F_HID) bb2[t] = b2[t];
    if (t < 8) gcnt[t] = 0;
    if (t < 8 * F_HID) ((float*)acc2)[t] = 0.0f;
    if (t == 0) pg0 = batch[w * 32];
    __syncthreads();
    int g0 = pg0;
    int half = (t >> 2) & 1, j = t & 3, nl = t >> 3;
    int i = w * 32 + nl;
    int2 rc = rowbc[i];
    float4 acc = row_gather8s((const ushort4*)pb, i, j, half, rc.x, rc.y, col);
    acc.x += __shfl_xor(acc.x, 4, 64);
    acc.y += __shfl_xor(acc.y, 4, 64);
    acc.z += __shfl_xor(acc.z, 4, 64);
    acc.w += __shfl_xor(acc.w, 4, 64);
    if (half == 0) {
        float di = dinv[i];
        float h0 = fmaxf(di * acc.x + bb2[4 * j + 0], 0.0f);
        float h1 = fmaxf(di * acc.y + bb2[4 * j + 1], 0.0f);
        float h2 = fmaxf(di * acc.z + bb2[4 * j + 2], 0.0f);
        float h3 = fmaxf(di * acc.w + bb2[4 * j + 3], 0.0f);
        int g = batch[i];
        int l = g - g0;
        if (l >= 0 && l < 8) {
            atomicAdd(&acc2[l][4 * j + 0], h0);
            atomicAdd(&acc2[l][4 * j + 1], h1);
            atomicAdd(&acc2[l][4 * j + 2], h2);
            atomicAdd(&acc2[l][4 * j + 3], h3);
            if (j == 0) atomicAdd(&gcnt[l], 1);
        } else {
            float inv = 1.0f / cnt[g];
            atomicAdd(&out[g * F_HID + 4 * j + 0], h0 * inv);
            atomicAdd(&out[g * F_HID + 4 * j + 1], h1 * inv);
            atomicAdd(&out[g * F_HID + 4 * j + 2], h2 * inv);
            atomicAdd(&out[g * F_HID + 4 * j + 3], h3 * inv);
        }
    }
    __syncthreads();
    if (t < 8 * F_HID) {
        int l = t >> 4, c = t & 15;
        if (gcnt[l] > 0) {
            float inv = 1.0f / cnt[g0 + l];
            atomicAdd(&out[(g0 + l) * F_HID + c], acc2[l][c] * inv);
        }
    }
    __syncthreads();
}

// ---------------- fused cooperative kernel ----------------

__global__ __launch_bounds__(NTHR, 4)
void k_fused(const int* src, const int* dst, const int* batch, const float* x,
             const float* W1, const float* b1, const float* W2, const float* b2,
             int* cursor, unsigned* packed, int2* rowbc, int* col, float* dinv,
             unsigned short* pb_a, unsigned short* pb_b, float* cnt, float* out) {
    cg::grid_group grid = cg::this_grid();
    int bid = blockIdx.x, t = threadIdx.x, nblk = gridDim.x;
    int gstep = nblk * NTHR, gidx = bid * NTHR + t;
    for (int i = gidx; i < NBKT * SHARDS; i += gstep) cursor[i] = 0;
    for (int i = gidx; i < N_GRAPHS * F_HID; i += gstep) out[i] = 0.0f;
    for (int i = gidx; i < N_GRAPHS; i += gstep) cnt[i] = 0.0f;
    for (int i = gidx; i < F_HID; i += gstep) {
        pb_a[(size_t)N_NODES * F_HID + i] = 0;
        pb_b[(size_t)N_NODES * F_HID + i] = 0;
    }
    grid.sync();
    for (int c = bid; c < NCHUNK; c += nblk)
        phase_part(c, src, dst, batch, cursor, packed, cnt);
    grid.sync();
    for (int b = bid; b < NBKT; b += nblk)
        phase_csr(b, cursor, packed, x, W1, rowbc, col, dinv, pb_a);
    grid.sync();
    for (int w = bid; w < NWIN; w += nblk)
        phase_mid(w, rowbc, col, pb_a, dinv, W2, b1, pb_b);
    grid.sync();
    for (int w = bid; w < NWIN; w += nblk)
        phase_pool(w, rowbc, col, pb_b, dinv, batch, b2, cnt, out);
}

// ---------------- split fallback kernels ----------------

__global__ __launch_bounds__(NTHR) void k_zero_s(int* cursor, float* out, float* cnt,
                                                 unsigned short* pb_a,
                                                 unsigned short* pb_b) {
    int i = blockIdx.x * NTHR + threadIdx.x;
    if (i < NBKT * SHARDS) cursor[i] = 0;
    if (i < N_GRAPHS * F_HID) out[i] = 0.0f;
    if (i < N_GRAPHS) cnt[i] = 0.0f;
    if (i < F_HID) {
        pb_a[(size_t)N_NODES * F_HID + i] = 0;
        pb_b[(size_t)N_NODES * F_HID + i] = 0;
    }
}
__global__ __launch_bounds__(NTHR) void k_part_s(const int* src, const int* dst,
                                                 const int* batch, int* cursor,
                                                 unsigned* packed, float* cnt) {
    phase_part(blockIdx.x, src, dst, batch, cursor, packed, cnt);
}
__global__ __launch_bounds__(NTHR) void k_csr_s(const int* cursor,
                                                const unsigned* packed,
                                                const float* x, const float* W1,
                                                int2* rowbc, int* col, float* dinv,
                                                unsigned short* pb) {
    phase_csr(blockIdx.x, cursor, packed, x, W1, rowbc, col, dinv, pb);
}
__global__ __launch_bounds__(NTHR) void k_mid_s(const int2* rowbc, const int* col,
                                                const unsigned short* pb,
                                                const float* dinv, const float* W2,
                                                const float* b1,
                                                unsigned short* pb2) {
    phase_mid(blockIdx.x, rowbc, col, pb, dinv, W2, b1, pb2);
}
__global__ __launch_bounds__(NTHR) void k_pool_s(const int2* rowbc, const int* col,
                                                 const unsigned short* pb,
                                                 const float* dinv, const int* batch,
                                                 const float* b2, const float* cnt,
                                                 float* out) {
    phase_pool(blockIdx.x, rowbc, col, pb, dinv, batch, b2, cnt, out);
}

// ---------------- launcher ----------------

extern "C" void kernel_launch(void* const* d_in, const int* in_sizes, int n_in,
                              void* d_out, int out_size, void* d_ws, size_t ws_size,
                              hipStream_t stream) {
    const float* x     = (const float*)d_in[0];
    const int*   ei    = (const int*)d_in[1];   // [2, N_EDGES]
    const int*   batch = (const int*)d_in[2];
    const float* W1    = (const float*)d_in[3];
    const float* b1    = (const float*)d_in[4];
    const float* W2    = (const float*)d_in[5];
    const float* b2    = (const float*)d_in[6];
    float* out = (float*)d_out;

    int*            cursor = (int*)d_ws;                                   // NBKT*8 (pad 6400)
    unsigned*       packed = (unsigned*)(cursor + 6400);                   // NBKT*CAP
    int2*           rowbc  = (int2*)(packed + (size_t)NBKT * CAP);         // N int2
    int*            col    = (int*)(rowbc + N_NODES);                      // NBKT*CAP
    float*          dinv   = (float*)(col + (size_t)NBKT * CAP);           // N
    unsigned short* pb_a   = (unsigned short*)(dinv + N_NODES);            // (N+1)*16
    unsigned short* pb_b   = pb_a + (size_t)(N_NODES + 1) * F_HID;         // (N+1)*16
    float*          cnt    = (float*)(pb_b + (size_t)(N_NODES + 1) * F_HID); // 512

    const int* src = ei;
    const int* dst = ei + N_EDGES;

    // try occupancy-clamped cooperative launch
    bool ok = false;
    int maxBlk = 0;
    hipError_t qe = hipOccupancyMaxActiveBlocksPerMultiprocessor(&maxBlk, k_fused,
                                                                 NTHR, 0);
    if (qe == hipSuccess && maxBlk > 0) {
        int nblk = maxBlk * 256;                 // 256 CUs on MI355X
        if (nblk > 1024) nblk = 1024;
        void* args[] = {(void*)&src, (void*)&dst, (void*)&batch, (void*)&x,
                        (void*)&W1, (void*)&b1, (void*)&W2, (void*)&b2,
                        (void*)&cursor, (void*)&packed, (void*)&rowbc, (void*)&col,
                        (void*)&dinv, (void*)&pb_a, (void*)&pb_b, (void*)&cnt,
                        (void*)&out};
        ok = hipLaunchCooperativeKernel((void*)k_fused, dim3(nblk), dim3(NTHR),
                                        args, 0, stream) == hipSuccess;
    }
    if (!ok) {                                   // proven split pipeline
        k_zero_s<<<(N_GRAPHS * F_HID + NTHR - 1) / NTHR, NTHR, 0, stream>>>(
            cursor, out, cnt, pb_a, pb_b);
        k_part_s<<<NCHUNK, NTHR, 0, stream>>>(src, dst, batch, cursor, packed, cnt);
        k_csr_s<<<NBKT, NTHR, 0, stream>>>(cursor, packed, x, W1, rowbc, col,
                                           dinv, pb_a);
        k_mid_s<<<NWIN, NTHR, 0, stream>>>(rowbc, col, pb_a, dinv, W2, b1, pb_b);
        k_pool_s<<<NWIN, NTHR, 0, stream>>>(rowbc, col, pb_b, dinv, batch, b2,
                                            cnt, out);
    }
}

// Round 15
// 200.317 us; speedup vs baseline: 2.6180x; 2.6180x over previous
//
#include <hip/hip_runtime.h>

#define N_NODES  100000
#define N_EDGES  3200000
#define N_GRAPHS 512
#define F_IN     5
#define F_HID    16

#define PBLK   512                      // k_part block size
#define CHUNK  4096                     // edges per k_part chunk
#define EPT    (CHUNK / PBLK)           // 8
#define NCHUNK ((N_EDGES + CHUNK - 1) / CHUNK)          // 782
#define CNT_NODES 128                   // nodes per k_part block for graph counting
#define BKT_NODES 256                   // nodes per coarse bucket
#define NBKT ((N_NODES + BKT_NODES - 1) / BKT_NODES)    // 391
#define SHARDS 8                        // cursor shards per bucket
#define CAP_S  1280                     // per-(bucket,shard): mean 1023, +8 sigma
#define CAP    (SHARDS * CAP_S)         // 10240 per bucket
#define UNR    (CAP / 512)              // 20 k_csr iterations
#define NCOPY  8                        // pb copies (one per XCD)
#define PBSTRIDE ((size_t)(N_NODES + 1) * F_HID)   // ushorts per copy

// ---------------- helpers ----------------

__device__ inline unsigned short f2bf(float f) {
    unsigned u = __float_as_uint(f);
    return (unsigned short)((u + 0x7fffu + ((u >> 16) & 1u)) >> 16);   // RNE
}
__device__ inline float bf2f(unsigned short h) {
    return __uint_as_float(((unsigned)h) << 16);
}
__device__ inline float4 cvt4(ushort4 u) {
    return make_float4(bf2f(u.x), bf2f(u.y), bf2f(u.z), bf2f(u.w));
}
__device__ inline float4 shfl_xor4(float4 v, int m) {
    return make_float4(__shfl_xor(v.x, m, 64), __shfl_xor(v.y, m, 64),
                       __shfl_xor(v.z, m, 64), __shfl_xor(v.w, m, 64));
}

// block-wide inclusive scan via wave shfl; NW = number of waves (<=8)
template <int NW>
__device__ inline int block_incl_scan(int v, int t, int* wsum) {
    int lane = t & 63, wave = t >> 6;
    int x = v;
#pragma unroll
    for (int o = 1; o < 64; o <<= 1) {
        int y = __shfl_up(x, o, 64);
        if (lane >= o) x += y;
    }
    if (lane == 63) wsum[wave] = x;
    __syncthreads();
    if (t < 64) {
        int w = (t < NW) ? wsum[t] : 0;
#pragma unroll
        for (int o = 1; o < NW; o <<= 1) {
            int y = __shfl_up(w, o, 64);
            if (t >= o) w += y;
        }
        if (t < NW) wsum[t] = w;
    }
    __syncthreads();
    return x + (wave ? wsum[wave - 1] : 0);
}

// half-row gather (len % 8 == 0): half h takes 8-blocks h, h+2, ... (R9-proven)
__device__ inline float4 row_gather8s(const ushort4* __restrict__ pb4, int i, int j,
                                      int half, int beg, int len,
                                      const int* __restrict__ col) {
    float4 acc = half ? make_float4(0.f, 0.f, 0.f, 0.f)
                      : cvt4(pb4[i * 4 + j]);          // self loop once
    for (int k = half * 8; k < len; k += 16) {
        int4 c0 = *(const int4*)(col + beg + k);
        int4 c1 = *(const int4*)(col + beg + k + 4);
        ushort4 a0 = pb4[c0.x * 4 + j], a1 = pb4[c0.y * 4 + j];
        ushort4 a2 = pb4[c0.z * 4 + j], a3 = pb4[c0.w * 4 + j];
        ushort4 a4 = pb4[c1.x * 4 + j], a5 = pb4[c1.y * 4 + j];
        ushort4 a6 = pb4[c1.z * 4 + j], a7 = pb4[c1.w * 4 + j];
        float4 f0 = cvt4(a0), f1 = cvt4(a1), f2 = cvt4(a2), f3 = cvt4(a3);
        float4 f4 = cvt4(a4), f5 = cvt4(a5), f6 = cvt4(a6), f7 = cvt4(a7);
        acc.x += ((f0.x + f1.x) + (f2.x + f3.x)) + ((f4.x + f5.x) + (f6.x + f7.x));
        acc.y += ((f0.y + f1.y) + (f2.y + f3.y)) + ((f4.y + f5.y) + (f6.y + f7.y));
        acc.z += ((f0.z + f1.z) + (f2.z + f3.z)) + ((f4.z + f5.z) + (f6.z + f7.z));
        acc.w += ((f0.w + f1.w) + (f2.w + f3.w)) + ((f4.w + f5.w) + (f6.w + f7.w));
    }
    return acc;
}

// ---------------- kernels ----------------

__global__ void k_zero(int* __restrict__ cursor, float* __restrict__ out,
                       float* __restrict__ cnt, unsigned short* __restrict__ pb_a,
                       unsigned short* __restrict__ pb_b) {
    int i = blockIdx.x * blockDim.x + threadIdx.x;
    if (i < NBKT * SHARDS) cursor[i] = 0;
    if (i < N_GRAPHS * F_HID) out[i] = 0.0f;
    if (i < N_GRAPHS) cnt[i] = 0.0f;
    if (i < F_HID * NCOPY) {               // zero dummy rows in every copy
        int c = i / F_HID, q = i % F_HID;
        pb_a[c * PBSTRIDE + (size_t)N_NODES * F_HID + q] = 0;
        pb_b[c * PBSTRIDE + (size_t)N_NODES * F_HID + q] = 0;
    }
}

// rank-capture counting-sort partition into 391 coarse buckets of dst>>8.
// 8-way sharded reservation cursors; also counts nodes-per-graph.
__global__ __launch_bounds__(PBLK) void k_part(const int* __restrict__ src,
                                               const int* __restrict__ dst,
                                               const int* __restrict__ batch,
                                               int* __restrict__ cursor,
                                               unsigned* __restrict__ packed,
                                               float* __restrict__ cnt) {
    __shared__ int hist[NBKT];
    __shared__ int gbase[NBKT];
    __shared__ int bcnt[8];
    __shared__ int g0s;
    int t = threadIdx.x;
    int blk = blockIdx.x;
    int s = blk & (SHARDS - 1);
    int chunk0 = blk * CHUNK;
    int n = min(CHUNK, N_EDGES - chunk0);
    if (t < NBKT) hist[t] = 0;
    if (t < 8) bcnt[t] = 0;
    if (t == 0) {
        int nb = blk * CNT_NODES;
        g0s = batch[nb < N_NODES ? nb : N_NODES - 1];
    }
    __syncthreads();
    int ls[EPT], ld[EPT], lr[EPT];
#pragma unroll
    for (int idx = 0; idx < EPT; idx++) {
        int k = t + idx * PBLK;
        if (k < n) {
            ls[idx] = src[chunk0 + k];
            ld[idx] = dst[chunk0 + k];
            lr[idx] = atomicAdd(&hist[ld[idx] >> 8], 1);   // rank capture
        }
    }
    if (t < CNT_NODES) {                 // graph-size count for node window
        int i2 = blk * CNT_NODES + t;
        if (i2 < N_NODES) {
            int g = batch[i2];
            int l = g - g0s;
            if (l >= 0 && l < 8) atomicAdd(&bcnt[l], 1);
            else atomicAdd(&cnt[g], 1.0f);
        }
    }
    __syncthreads();
    if (t < NBKT) {
        int v = hist[t];
        gbase[t] = (v > 0) ? atomicAdd(&cursor[t * SHARDS + s], v) : 0;
    }
    if (t < 8 && bcnt[t] > 0) atomicAdd(&cnt[g0s + t], (float)bcnt[t]);
    __syncthreads();
#pragma unroll
    for (int idx = 0; idx < EPT; idx++) {
        int k = t + idx * PBLK;
        if (k < n) {
            int b = ld[idx] >> 8;
            int g = gbase[b] + lr[idx];
            if (g < CAP_S)
                packed[(size_t)b * CAP + s * CAP_S + g] =
                    ((unsigned)ls[idx] << 8) | (unsigned)(ld[idx] & 255);
        }
    }
}

// per coarse bucket: two-pass counting sort (8 shard segments) into BUCKET-LOCAL
// col (rows padded to %8 with dummy node N_NODES); emits (beg,len), dinv,
// and fused layer-1 transform pb = bf16((x @ W1) * dinv) to ALL NCOPY copies
__global__ __launch_bounds__(512) void k_csr(const int* __restrict__ cursor,
                                             const unsigned* __restrict__ packed,
                                             const float* __restrict__ x,
                                             const float* __restrict__ W1,
                                             int2* __restrict__ rowbc,
                                             int* __restrict__ col,
                                             float* __restrict__ dinv,
                                             unsigned short* __restrict__ pb) {
    __shared__ int hist[BKT_NODES];
    __shared__ int rnk[BKT_NODES];
    __shared__ int wsum[8];
    __shared__ int ns[SHARDS];
    __shared__ float w1[F_IN * F_HID];
    int b = blockIdx.x, t = threadIdx.x;
    int base = b * CAP;
    if (t < BKT_NODES) hist[t] = 0;
    if (t < SHARDS) ns[t] = min(cursor[b * SHARDS + t], CAP_S);
    if (t < F_IN * F_HID) w1[t] = W1[t];
    __syncthreads();
    const unsigned* pk = packed + (size_t)b * CAP;
#pragma unroll
    for (int s = 0; s < SHARDS; s++) {
        int m = ns[s];
        const unsigned* pks = pk + s * CAP_S;
        for (int k = t; k < m; k += 512)
            atomicAdd(&hist[pks[k] & 255], 1);
    }
    __syncthreads();
    int v = (t < BKT_NODES) ? hist[t] : 0;
    int len = (v + 7) & ~7;                       // padded row length
    int incl = block_incl_scan<8>(len, t, wsum);
    int excl = incl - len;
    if (t < BKT_NODES) rnk[t] = excl;
    __syncthreads();
#pragma unroll
    for (int s = 0; s < SHARDS; s++) {
        int m = ns[s];
        const unsigned* pks = pk + s * CAP_S;
        for (int k = t; k < m; k += 512) {
            unsigned w = pks[k];
            int r = atomicAdd(&rnk[w & 255], 1);
            if (r < CAP) col[base + r] = (int)(w >> 8);
        }
    }
    if (t < BKT_NODES) {
        int node = b * BKT_NODES + t;
        if (node < N_NODES) {
            int mylen = min(len, ((CAP - min(excl, CAP)) & ~7));
            for (int q = v; q < mylen; q++) {     // pad with dummy node
                int r = excl + q;
                if (r < CAP) col[base + r] = N_NODES;
            }
            rowbc[node] = make_int2(base + excl, mylen);
            float di = rsqrtf((float)(1 + v));
            dinv[node] = di;
            float xi[F_IN];
#pragma unroll
            for (int k = 0; k < F_IN; k++) xi[k] = x[node * F_IN + k];
            float hv[F_HID];
#pragma unroll
            for (int c = 0; c < F_HID; c++) {
                float h = 0.0f;
#pragma unroll
                for (int k = 0; k < F_IN; k++) h += xi[k] * w1[k * F_HID + c];
                hv[c] = h * di;
            }
            unsigned pkk[8];
#pragma unroll
            for (int q = 0; q < 8; q++)
                pkk[q] = (unsigned)f2bf(hv[2 * q]) | ((unsigned)f2bf(hv[2 * q + 1]) << 16);
            uint4 lo = make_uint4(pkk[0], pkk[1], pkk[2], pkk[3]);
            uint4 hi4 = make_uint4(pkk[4], pkk[5], pkk[6], pkk[7]);
#pragma unroll
            for (int cp = 0; cp < NCOPY; cp++) {
                uint4* d4 = (uint4*)(pb + cp * PBSTRIDE + (size_t)node * F_HID);
                d4[0] = lo;
                d4[1] = hi4;
            }
        }
    }
}

// fused pull + layer-1 epilogue + layer-2 transform; 8 threads/node;
// reads XCD-local copy, writes all NCOPY copies of pb2
__global__ __launch_bounds__(256) void k_pull_mid(const int2* __restrict__ rowbc,
                                                  const int* __restrict__ col,
                                                  const unsigned short* __restrict__ pb,
                                                  const float* __restrict__ dinv,
                                                  const float* __restrict__ W2,
                                                  const float* __restrict__ b1,
                                                  unsigned short* __restrict__ pb2) {
    __shared__ float w[F_HID * F_HID];
    __shared__ float bb[F_HID];
    int t = threadIdx.x;
    w[t] = W2[t];                        // blockDim == 256 == F_HID*F_HID
    if (t < F_HID) bb[t] = b1[t];
    __syncthreads();
    const unsigned short* pbl = pb + (blockIdx.x & (NCOPY - 1)) * PBSTRIDE;
    int gid = blockIdx.x * 256 + t;      // grid = N_NODES*8/256 exactly
    int i = gid >> 3;
    int half = (gid >> 2) & 1;
    int j = gid & 3;
    int2 rc = rowbc[i];
    float4 acc = row_gather8s((const ushort4*)pbl, i, j, half, rc.x, rc.y, col);
    acc.x += __shfl_xor(acc.x, 4, 64);
    acc.y += __shfl_xor(acc.y, 4, 64);
    acc.z += __shfl_xor(acc.z, 4, 64);
    acc.w += __shfl_xor(acc.w, 4, 64);
    float di = dinv[i];
    float4 mine;
    mine.x = fmaxf(di * acc.x + bb[4 * j + 0], 0.0f);
    mine.y = fmaxf(di * acc.y + bb[4 * j + 1], 0.0f);
    mine.z = fmaxf(di * acc.z + bb[4 * j + 2], 0.0f);
    mine.w = fmaxf(di * acc.w + bb[4 * j + 3], 0.0f);
    float4 o1 = shfl_xor4(mine, 1);
    float4 o2 = shfl_xor4(mine, 2);
    float4 o3 = shfl_xor4(mine, 3);
    float4 hq0 = (j == 0) ? mine : ((j == 1) ? o1 : ((j == 2) ? o2 : o3));
    float4 hq1 = (j == 1) ? mine : ((j == 0) ? o1 : ((j == 3) ? o2 : o3));
    float4 hq2 = (j == 2) ? mine : ((j == 3) ? o1 : ((j == 0) ? o2 : o3));
    float4 hq3 = (j == 3) ? mine : ((j == 2) ? o1 : ((j == 1) ? o2 : o3));
    float hc[F_HID] = {hq0.x, hq0.y, hq0.z, hq0.w, hq1.x, hq1.y, hq1.z, hq1.w,
                       hq2.x, hq2.y, hq2.z, hq2.w, hq3.x, hq3.y, hq3.z, hq3.w};
    float m0 = 0.0f, m1 = 0.0f, m2 = 0.0f, m3 = 0.0f;
#pragma unroll
    for (int c = 0; c < F_HID; c++) {
        float4 wv = *(const float4*)&w[c * F_HID + 4 * j];
        float hv = hc[c];
        m0 += hv * wv.x; m1 += hv * wv.y; m2 += hv * wv.z; m3 += hv * wv.w;
    }
    if (half == 0) {
        unsigned p0 = (unsigned)f2bf(m0 * di) | ((unsigned)f2bf(m1 * di) << 16);
        unsigned p1 = (unsigned)f2bf(m2 * di) | ((unsigned)f2bf(m3 * di) << 16);
        uint2 pv = make_uint2(p0, p1);
#pragma unroll
        for (int cp = 0; cp < NCOPY; cp++)
            *(uint2*)(pb2 + cp * PBSTRIDE + (size_t)i * F_HID + 4 * j) = pv;
    }
}

// fused pull + layer-2 epilogue + mean-pool; 8 thr/node; XCD-local copy read
__global__ __launch_bounds__(256) void k_pull_pool(const int2* __restrict__ rowbc,
                                                   const int* __restrict__ col,
                                                   const unsigned short* __restrict__ pb,
                                                   const float* __restrict__ dinv,
                                                   const int* __restrict__ batch,
                                                   const float* __restrict__ b2,
                                                   const float* __restrict__ cnt,
                                                   float* __restrict__ out) {
    __shared__ float bb[F_HID];
    __shared__ float acc2[8][F_HID];
    __shared__ int gcnt[8];
    __shared__ int g0s;
    int t = threadIdx.x;
    if (t < F_HID) bb[t] = b2[t];
    if (t < 8) gcnt[t] = 0;
    if (t < 8 * F_HID) ((float*)acc2)[t] = 0.0f;
    int blk0node = blockIdx.x * 32;                 // 32 nodes per block
    if (t == 0) g0s = batch[blk0node < N_NODES ? blk0node : N_NODES - 1];
    __syncthreads();
    const unsigned short* pbl = pb + (blockIdx.x & (NCOPY - 1)) * PBSTRIDE;
    int g0 = g0s;
    int gid = blockIdx.x * 256 + t;
    int i = gid >> 3;
    int half = (gid >> 2) & 1;
    int j = gid & 3;
    int2 rc = rowbc[i];
    float4 acc = row_gather8s((const ushort4*)pbl, i, j, half, rc.x, rc.y, col);
    acc.x += __shfl_xor(acc.x, 4, 64);
    acc.y += __shfl_xor(acc.y, 4, 64);
    acc.z += __shfl_xor(acc.z, 4, 64);
    acc.w += __shfl_xor(acc.w, 4, 64);
    if (half == 0) {
        float di = dinv[i];
        float h0 = fmaxf(di * acc.x + bb[4 * j + 0], 0.0f);
        float h1 = fmaxf(di * acc.y + bb[4 * j + 1], 0.0f);
        float h2 = fmaxf(di * acc.z + bb[4 * j + 2], 0.0f);
        float h3 = fmaxf(di * acc.w + bb[4 * j + 3], 0.0f);
        int g = batch[i];
        int l = g - g0;
        if (l >= 0 && l < 8) {
            atomicAdd(&acc2[l][4 * j + 0], h0);
            atomicAdd(&acc2[l][4 * j + 1], h1);
            atomicAdd(&acc2[l][4 * j + 2], h2);
            atomicAdd(&acc2[l][4 * j + 3], h3);
            if (j == 0) atomicAdd(&gcnt[l], 1);
        } else {
            float inv = 1.0f / cnt[g];
            atomicAdd(&out[g * F_HID + 4 * j + 0], h0 * inv);
            atomicAdd(&out[g * F_HID + 4 * j + 1], h1 * inv);
            atomicAdd(&out[g * F_HID + 4 * j + 2], h2 * inv);
            atomicAdd(&out[g * F_HID + 4 * j + 3], h3 * inv);
        }
    }
    __syncthreads();
    if (t < 8 * F_HID) {
        int l = t >> 4, c = t & 15;
        if (gcnt[l] > 0) {
            float inv = 1.0f / cnt[g0 + l];
            atomicAdd(&out[(g0 + l) * F_HID + c], acc2[l][c] * inv);
        }
    }
}

// ---------------- launcher ----------------

extern "C" void kernel_launch(void* const* d_in, const int* in_sizes, int n_in,
                              void* d_out, int out_size, void* d_ws, size_t ws_size,
                              hipStream_t stream) {
    const float* x     = (const float*)d_in[0];
    const int*   ei    = (const int*)d_in[1];   // [2, N_EDGES]
    const int*   batch = (const int*)d_in[2];
    const float* W1    = (const float*)d_in[3];
    const float* b1    = (const float*)d_in[4];
    const float* W2    = (const float*)d_in[5];
    const float* b2    = (const float*)d_in[6];
    float* out = (float*)d_out;

    int*            cursor = (int*)d_ws;                                   // NBKT*8 (pad 3200)
    unsigned*       packed = (unsigned*)(cursor + 3200);                   // NBKT*CAP
    int2*           rowbc  = (int2*)(packed + (size_t)NBKT * CAP);         // N int2
    int*            col    = (int*)(rowbc + N_NODES);                      // NBKT*CAP
    float*          dinv   = (float*)(col + (size_t)NBKT * CAP);           // N
    unsigned short* pb_a   = (unsigned short*)(dinv + N_NODES);            // 8 copies
    unsigned short* pb_b   = pb_a + NCOPY * PBSTRIDE;                      // 8 copies
    float*          cnt    = (float*)(pb_b + NCOPY * PBSTRIDE);            // 512

    const int* src = ei;
    const int* dst = ei + N_EDGES;

    const int nb_pull = (N_NODES * 8) / 256;        // 3125 exactly

    k_zero<<<(N_GRAPHS * F_HID + 255) / 256, 256, 0, stream>>>(cursor, out, cnt,
                                                               pb_a, pb_b);
    k_part<<<NCHUNK, PBLK, 0, stream>>>(src, dst, batch, cursor, packed, cnt);
    k_csr<<<NBKT, 512, 0, stream>>>(cursor, packed, x, W1, rowbc, col, dinv, pb_a);
    k_pull_mid<<<nb_pull, 256, 0, stream>>>(rowbc, col, pb_a, dinv, W2, b1, pb_b);
    k_pull_pool<<<nb_pull, 256, 0, stream>>>(rowbc, col, pb_b, dinv, batch, b2,
                                             cnt, out);
}